// Round 9
// baseline (305.333 us; speedup 1.0000x reference)
//
#include <hip/hip_runtime.h>
#include <cstdint>
#include <cstddef>

#define NB 16
#define NL 2048
#define ND 64
#define QT 16                 // q rows per workgroup
#define NW 8                  // waves per workgroup
#define NTHREADS (NW * 64)
#define SLICE (NL / NW)       // 256 k-cols per wave
#define NT (SLICE / 16)       // 16 MFMA col-tiles per wave

typedef __attribute__((ext_vector_type(8))) short bf16x8;
typedef __attribute__((ext_vector_type(4))) float f32x4;
typedef __attribute__((ext_vector_type(4))) int i32x4;
typedef __attribute__((ext_vector_type(4))) unsigned short u16x4;
typedef unsigned short u16;

#define MFMA __builtin_amdgcn_mfma_f32_16x16x32_bf16

__device__ __forceinline__ u16 f2bf(float x) {
  union { float f; uint32_t u; } v; v.f = x;
  uint32_t r = v.u + 0x7FFFu + ((v.u >> 16) & 1u);   // RNE
  return (u16)(r >> 16);
}
__device__ __forceinline__ float bfhi2f(uint32_t w) {
  union { uint32_t u; float f; } v; v.u = w & 0xFFFF0000u; return v.f;
}
__device__ __forceinline__ float bflo2f(uint32_t w) {
  union { uint32_t u; float f; } v; v.u = w << 16; return v.f;
}

// Load mask nibble for 4 consecutive k at element index i. MODE: 0=i32,1=u8,2=f32,3=i64
template <int MODE>
__device__ __forceinline__ uint32_t mnib(const void* __restrict__ m, size_t i) {
  if constexpr (MODE == 1) {
    const uint32_t x = __builtin_nontemporal_load((const uint32_t*)((const uint8_t*)m + i));
    return (x | (x >> 7) | (x >> 14) | (x >> 21)) & 0xFu;
  } else if constexpr (MODE == 0) {
    const i32x4 x = __builtin_nontemporal_load(((const i32x4*)((const int*)m + i)));
    return (uint32_t)(x[0] != 0) | ((uint32_t)(x[1] != 0) << 1) |
           ((uint32_t)(x[2] != 0) << 2) | ((uint32_t)(x[3] != 0) << 3);
  } else if constexpr (MODE == 2) {
    const f32x4 x = __builtin_nontemporal_load(((const f32x4*)((const float*)m + i)));
    return (uint32_t)(x[0] != 0.f) | ((uint32_t)(x[1] != 0.f) << 1) |
           ((uint32_t)(x[2] != 0.f) << 2) | ((uint32_t)(x[3] != 0.f) << 3);
  } else {
    const uint32_t* p = (const uint32_t*)m + 2 * i;   // i64: low dword is 0/1
    return (uint32_t)(p[0] != 0u) | ((uint32_t)(p[2] != 0u) << 1) |
           ((uint32_t)(p[4] != 0u) << 2) | ((uint32_t)(p[6] != 0u) << 3);
  }
}

template <bool WS>
__device__ __forceinline__ void loadKfrag(const float* __restrict__ k,
                                          const u16* __restrict__ kb,
                                          int b, int row, int kg,
                                          bf16x8& b0, bf16x8& b1) {
  if constexpr (WS) {
    const u16* kp = kb + ((size_t)(b * NL + row)) * ND + kg * 8;
    b0 = *(const bf16x8*)kp;
    b1 = *(const bf16x8*)(kp + 32);
  } else {
    const float* kp = k + ((size_t)(b * NL + row)) * ND + kg * 8;
#pragma unroll
    for (int i = 0; i < 8; ++i) {
      b0[i] = (short)f2bf(kp[i]);
      b1[i] = (short)f2bf(kp[i + 32]);
    }
  }
}

template <int MODE, bool WS>
__device__ __forceinline__ void attn_body(
    const float* __restrict__ q, const float* __restrict__ k,
    const float* __restrict__ v, const float* __restrict__ ew,
    const void* __restrict__ mask,
    const u16* __restrict__ qs, const u16* __restrict__ kb,
    const u16* __restrict__ vt,
    float* __restrict__ out, float* __restrict__ attn,
    float* __restrict__ osta, float* __restrict__ rsums) {
  const int tid = threadIdx.x;
  const int lane = tid & 63;
  const int w = tid >> 6;
  const int fr = lane & 15;   // q-row within tile (S^T output col)
  const int kg = lane >> 4;   // lane group 0..3

  // XCD-aware bijective swizzle (2048 WGs, 8 XCDs -> 2 whole batches per XCD)
  const int bid = blockIdx.x;
  const int swz = (bid & 7) * ((NB * (NL / QT)) / 8) + (bid >> 3);
  const int b = swz >> 7;               // 128 q-tiles per batch
  const int q0 = (swz & 127) * QT;
  const int cbase = w * SLICE;
  const size_t mrow0 = ((size_t)b * NL + q0) * NL;
  const size_t lrow = mrow0 + (size_t)fr * NL + (size_t)(cbase + 4 * kg);

  // Q fragments (temperature folded in)
  bf16x8 a0, a1;
  if constexpr (WS) {
    const u16* qp = qs + ((size_t)(b * NL + q0 + fr)) * ND + kg * 8;
    a0 = *(const bf16x8*)qp;
    a1 = *(const bf16x8*)(qp + 32);
  } else {
    const float* qp = q + ((size_t)(b * NL + q0 + fr)) * ND + kg * 8;
#pragma unroll
    for (int i = 0; i < 8; ++i) {
      a0[i] = (short)f2bf(qp[i] * 0.125f);
      a1[i] = (short)f2bf(qp[i + 32] * 0.125f);
    }
  }

  // ---- Phase A (single S pass): e = exp(masked S) kept packed in regs ----
  uint32_t epk[2 * NT];   // 32 regs: bf16-packed e, fully static indexing
  float rs = 0.f;
#pragma unroll
  for (int ti = 0; ti < NT; ++ti) {
    const int c0 = cbase + ti * 16;
    bf16x8 b0, b1;
    loadKfrag<WS>(k, kb, b, c0 + fr, kg, b0, b1);
    f32x4 s = {0.f, 0.f, 0.f, 0.f};
    s = MFMA(b0, a0, s, 0, 0, 0);   // S^T: lane holds S[q=fr][k=c0+4kg+j]
    s = MFMA(b1, a1, s, 0, 0, 0);
    const uint32_t nib = mnib<MODE>(mask, lrow + (size_t)(ti * 16));
    const float e0 = (nib & 1u) ? 0.f : __expf(s[0]);
    const float e1 = (nib & 2u) ? 0.f : __expf(s[1]);
    const float e2 = (nib & 4u) ? 0.f : __expf(s[2]);
    const float e3 = (nib & 8u) ? 0.f : __expf(s[3]);
    rs += (e0 + e1) + (e2 + e3);
    epk[2 * ti]     = (uint32_t)f2bf(e0) | ((uint32_t)f2bf(e1) << 16);
    epk[2 * ti + 1] = (uint32_t)f2bf(e2) | ((uint32_t)f2bf(e3) << 16);
  }
  rs += __shfl_xor(rs, 16, 64);
  rs += __shfl_xor(rs, 32, 64);
  if (lane < 16) rsums[w * QT + fr] = rs;
  __syncthreads();
  float inv = 0.f;
#pragma unroll
  for (int ww = 0; ww < NW; ++ww) inv += rsums[ww * QT + fr];
  inv = 1.0f / inv;

  // ---- Phase B1: pure streaming. p = e*inv*ew -> attn; repack p in-place ----
  const float* ewp = ew + lrow;
  float* atp = attn + lrow;
#pragma unroll
  for (int sg = 0; sg < NT; ++sg) {     // 16 independent 16B segments
    const f32x4 w4 = __builtin_nontemporal_load((const f32x4*)(ewp + sg * 16));
    f32x4 p;
    p[0] = bflo2f(epk[2 * sg])     * inv * w4[0];
    p[1] = bfhi2f(epk[2 * sg])     * inv * w4[1];
    p[2] = bflo2f(epk[2 * sg + 1]) * inv * w4[2];
    p[3] = bfhi2f(epk[2 * sg + 1]) * inv * w4[3];
    __builtin_nontemporal_store(p, (f32x4*)(atp + sg * 16));
    epk[2 * sg]     = (uint32_t)f2bf(p[0]) | ((uint32_t)f2bf(p[1]) << 16);
    epk[2 * sg + 1] = (uint32_t)f2bf(p[2]) | ((uint32_t)f2bf(p[3]) << 16);
  }

  // ---- Phase B2: register-only P transpose via shuffles + PV MFMA ----
  // lane (kg,fr) needs P[q=fr][k = 32gi + 8kg + 0..7]:
  //   tile = 2gi + (kg>>1); chunks m=2(kg&1), 2(kg&1)+1 -> src lanes fr+16m, fr+16m+16
  const int sA = fr + 16 * (2 * (kg & 1));
  const int sB = sA + 16;
  const bool tb = (kg >= 2);
  f32x4 oA[4] = {{0.f,0.f,0.f,0.f},{0.f,0.f,0.f,0.f},{0.f,0.f,0.f,0.f},{0.f,0.f,0.f,0.f}};
#pragma unroll
  for (int gi = 0; gi < NT / 2; ++gi) {
    const uint32_t x0 = (uint32_t)__shfl((int)epk[4 * gi],     sA, 64);
    const uint32_t x1 = (uint32_t)__shfl((int)epk[4 * gi + 1], sA, 64);
    const uint32_t x2 = (uint32_t)__shfl((int)epk[4 * gi],     sB, 64);
    const uint32_t x3 = (uint32_t)__shfl((int)epk[4 * gi + 1], sB, 64);
    const uint32_t y0 = (uint32_t)__shfl((int)epk[4 * gi + 2], sA, 64);
    const uint32_t y1 = (uint32_t)__shfl((int)epk[4 * gi + 3], sA, 64);
    const uint32_t y2 = (uint32_t)__shfl((int)epk[4 * gi + 2], sB, 64);
    const uint32_t y3 = (uint32_t)__shfl((int)epk[4 * gi + 3], sB, 64);
    union { uint32_t wd[4]; bf16x8 v; } pu;
    pu.wd[0] = tb ? y0 : x0;
    pu.wd[1] = tb ? y1 : x1;
    pu.wd[2] = tb ? y2 : x2;
    pu.wd[3] = tb ? y3 : x3;
    const bf16x8 pa = pu.v;
    const int kk = cbase + gi * 32 + kg * 8;
    if constexpr (WS) {
      const u16* vp = vt + ((size_t)(b * ND + fr)) * NL + kk;   // VT[d][k]
      oA[0] = MFMA(pa, *(const bf16x8*)(vp),           oA[0], 0, 0, 0);
      oA[1] = MFMA(pa, *(const bf16x8*)(vp + 16 * NL), oA[1], 0, 0, 0);
      oA[2] = MFMA(pa, *(const bf16x8*)(vp + 32 * NL), oA[2], 0, 0, 0);
      oA[3] = MFMA(pa, *(const bf16x8*)(vp + 48 * NL), oA[3], 0, 0, 0);
    } else {
#pragma unroll
      for (int dt = 0; dt < 4; ++dt) {
        bf16x8 vf;
#pragma unroll
        for (int i = 0; i < 8; ++i)
          vf[i] = (short)f2bf(v[((size_t)(b * NL + kk + i)) * ND + dt * 16 + fr]);
        oA[dt] = MFMA(pa, vf, oA[dt], 0, 0, 0);
      }
    }
  }

  // ---- 4-round staged cross-wave out reduction (8 KB LDS, 2 waves/round) ----
  f32x4 acc = {0.f, 0.f, 0.f, 0.f};
  const int r = tid >> 4;            // valid for tid < 256
  const int d4 = (tid & 15) * 4;
#pragma unroll
  for (int round = 0; round < NW / 2; ++round) {
    if ((w >> 1) == round) {
      float* od = osta + (w & 1) * (QT * ND);
#pragma unroll
      for (int dt = 0; dt < 4; ++dt)
#pragma unroll
        for (int j = 0; j < 4; ++j)
          od[(4 * kg + j) * ND + dt * 16 + fr] = oA[dt][j];
    }
    __syncthreads();
    if (tid < QT * ND / 4) {
      acc += *(const f32x4*)(osta + r * ND + d4) +
             *(const f32x4*)(osta + QT * ND + r * ND + d4);
    }
    __syncthreads();
  }
  if (tid < QT * ND / 4)
    *(f32x4*)(out + ((size_t)(b * NL + q0 + r)) * ND + d4) = acc;
}

template <bool WS>
__global__ void __launch_bounds__(NTHREADS)
attn_main(const float* __restrict__ q, const float* __restrict__ k,
          const float* __restrict__ v, const float* __restrict__ ew,
          const void* __restrict__ mask,
          const u16* __restrict__ qs, const u16* __restrict__ kb,
          const u16* __restrict__ vt,
          float* __restrict__ out, float* __restrict__ attn) {
  __shared__ float osta[2 * QT * ND];   // 8 KB: 2-wave staging, 4 rounds
  __shared__ float rsums[NW * QT];
  __shared__ int s_mode;
  if (threadIdx.x < 64) {
    const uint32_t x = ((const uint32_t*)mask)[threadIdx.x];
    const int all01 = __all(x <= 1u);
    const int allf  = __all(x == 0u || x == 0x3F800000u);
    const int oddz  = __all(((threadIdx.x & 1) == 0) || (x == 0u));
    if (threadIdx.x == 0) s_mode = all01 ? (oddz ? 3 : 0) : (allf ? 2 : 1);
  }
  __syncthreads();
  switch (s_mode) {
    case 0:  attn_body<0, WS>(q, k, v, ew, mask, qs, kb, vt, out, attn, osta, rsums); break;
    case 1:  attn_body<1, WS>(q, k, v, ew, mask, qs, kb, vt, out, attn, osta, rsums); break;
    case 2:  attn_body<2, WS>(q, k, v, ew, mask, qs, kb, vt, out, attn, osta, rsums); break;
    default: attn_body<3, WS>(q, k, v, ew, mask, qs, kb, vt, out, attn, osta, rsums); break;
  }
}

// prep: q*0.125 -> bf16 qs ; k -> bf16 kb   (f32x4 per thread)
__global__ void __launch_bounds__(256)
prep_qk(const float* __restrict__ q, const float* __restrict__ k,
        u16* __restrict__ qs, u16* __restrict__ kb) {
  const size_t NQ4 = (size_t)NB * NL * ND / 4;
  const size_t i = (size_t)blockIdx.x * 256 + threadIdx.x;
  f32x4 val;
  u16* dst;
  if (i < NQ4) {
    val = ((const f32x4*)q)[i];
    val *= 0.125f;
    dst = qs + i * 4;
  } else {
    val = ((const f32x4*)k)[i - NQ4];
    dst = kb + (i - NQ4) * 4;
  }
  u16x4 o;
#pragma unroll
  for (int j = 0; j < 4; ++j) o[j] = f2bf(val[j]);
  *(u16x4*)dst = o;
}

// prep: v -> bf16 V^T (per-batch 64x2048), LDS tile transpose
__global__ void __launch_bounds__(256)
prep_vt(const float* __restrict__ v, u16* __restrict__ vt) {
  __shared__ float t[64 * 68];
  const int b = blockIdx.y;
  const int k0 = blockIdx.x * 64;
  const int tid = threadIdx.x;
  const int rr = tid >> 4;
  const int c4 = (tid & 15) * 4;
#pragma unroll
  for (int i = 0; i < 4; ++i) {
    const int r = rr + 16 * i;
    const f32x4 val = *(const f32x4*)(v + ((size_t)(b * NL + k0 + r)) * ND + c4);
    *(f32x4*)(t + r * 68 + c4) = val;
  }
  __syncthreads();
#pragma unroll
  for (int i = 0; i < 4; ++i) {
    const int d = rr + 16 * i;
    u16x4 o;
#pragma unroll
    for (int j = 0; j < 4; ++j) o[j] = f2bf(t[(c4 + j) * 68 + d]);
    *(u16x4*)(vt + ((size_t)(b * ND + d)) * NL + k0 + c4) = o;
  }
}

extern "C" void kernel_launch(void* const* d_in, const int* in_sizes, int n_in,
                              void* d_out, int out_size, void* d_ws, size_t ws_size,
                              hipStream_t stream) {
  const float* q    = (const float*)d_in[0];
  const float* k    = (const float*)d_in[1];
  const float* v    = (const float*)d_in[2];
  const float* ew   = (const float*)d_in[3];
  const void*  mask = d_in[4];
  float* out  = (float*)d_out;
  float* attn = out + (size_t)NB * NL * ND;

  const size_t QE = (size_t)NB * NL * ND;   // 2M elements per matrix
  u16* qs = (u16*)d_ws;
  u16* kb = qs + QE;
  u16* vt = kb + QE;

  dim3 grid(NB * (NL / QT));   // 2048, 1-D for XCD swizzle
  if (ws_size >= 3 * QE * sizeof(u16)) {
    prep_qk<<<dim3((unsigned)(2 * QE / 4 / 256)), 256, 0, stream>>>(q, k, qs, kb);
    prep_vt<<<dim3(NL / 64, NB), 256, 0, stream>>>(v, vt);
    attn_main<true><<<grid, NTHREADS, 0, stream>>>(q, k, v, ew, mask, qs, kb, vt, out, attn);
  } else {
    attn_main<false><<<grid, NTHREADS, 0, stream>>>(q, k, v, ew, mask, nullptr, nullptr, nullptr, out, attn);
  }
}

// Round 10
// 303.923 us; speedup vs baseline: 1.0046x; 1.0046x over previous
//
#include <hip/hip_runtime.h>
#include <cstdint>
#include <cstddef>

#define NB 16
#define NL 2048
#define ND 64
#define QT 16                 // q rows per workgroup
#define NW 8                  // waves per workgroup
#define NTHREADS (NW * 64)
#define SLICE (NL / NW)       // 256 k-cols per wave
#define NT (SLICE / 16)       // 16 MFMA col-tiles per wave

typedef __attribute__((ext_vector_type(8))) short bf16x8;
typedef __attribute__((ext_vector_type(4))) float f32x4;
typedef __attribute__((ext_vector_type(4))) int i32x4;
typedef __attribute__((ext_vector_type(4))) unsigned short u16x4;
typedef unsigned short u16;

#define MFMA __builtin_amdgcn_mfma_f32_16x16x32_bf16

__device__ __forceinline__ u16 f2bf(float x) {
  union { float f; uint32_t u; } v; v.f = x;
  uint32_t r = v.u + 0x7FFFu + ((v.u >> 16) & 1u);   // RNE
  return (u16)(r >> 16);
}
__device__ __forceinline__ float bfhi2f(uint32_t w) {
  union { uint32_t u; float f; } v; v.u = w & 0xFFFF0000u; return v.f;
}
__device__ __forceinline__ float bflo2f(uint32_t w) {
  union { uint32_t u; float f; } v; v.u = w << 16; return v.f;
}

// Load mask nibble for 4 consecutive k at element index i. MODE: 0=i32,1=u8,2=f32,3=i64
template <int MODE>
__device__ __forceinline__ uint32_t mnib(const void* __restrict__ m, size_t i) {
  if constexpr (MODE == 1) {
    const uint32_t x = __builtin_nontemporal_load((const uint32_t*)((const uint8_t*)m + i));
    return (x | (x >> 7) | (x >> 14) | (x >> 21)) & 0xFu;
  } else if constexpr (MODE == 0) {
    const i32x4 x = __builtin_nontemporal_load(((const i32x4*)((const int*)m + i)));
    return (uint32_t)(x[0] != 0) | ((uint32_t)(x[1] != 0) << 1) |
           ((uint32_t)(x[2] != 0) << 2) | ((uint32_t)(x[3] != 0) << 3);
  } else if constexpr (MODE == 2) {
    const f32x4 x = __builtin_nontemporal_load(((const f32x4*)((const float*)m + i)));
    return (uint32_t)(x[0] != 0.f) | ((uint32_t)(x[1] != 0.f) << 1) |
           ((uint32_t)(x[2] != 0.f) << 2) | ((uint32_t)(x[3] != 0.f) << 3);
  } else {
    const uint32_t* p = (const uint32_t*)m + 2 * i;   // i64: low dword is 0/1
    return (uint32_t)(p[0] != 0u) | ((uint32_t)(p[2] != 0u) << 1) |
           ((uint32_t)(p[4] != 0u) << 2) | ((uint32_t)(p[6] != 0u) << 3);
  }
}

template <bool WS>
__device__ __forceinline__ void loadKfrag(const float* __restrict__ k,
                                          const u16* __restrict__ kb,
                                          int b, int row, int kg,
                                          bf16x8& b0, bf16x8& b1) {
  if constexpr (WS) {
    const u16* kp = kb + ((size_t)(b * NL + row)) * ND + kg * 8;
    b0 = *(const bf16x8*)kp;
    b1 = *(const bf16x8*)(kp + 32);
  } else {
    const float* kp = k + ((size_t)(b * NL + row)) * ND + kg * 8;
#pragma unroll
    for (int i = 0; i < 8; ++i) {
      b0[i] = (short)f2bf(kp[i]);
      b1[i] = (short)f2bf(kp[i + 32]);
    }
  }
}

template <int MODE, bool WS>
__device__ __forceinline__ void attn_body(
    const float* __restrict__ q, const float* __restrict__ k,
    const float* __restrict__ v, const float* __restrict__ ew,
    const void* __restrict__ mask,
    const u16* __restrict__ qs, const u16* __restrict__ kb,
    const u16* __restrict__ vt,
    float* __restrict__ out, float* __restrict__ attn,
    float* __restrict__ osta, float* __restrict__ rsums) {
  const int tid = threadIdx.x;
  const int lane = tid & 63;
  const int w = tid >> 6;
  const int fr = lane & 15;   // q-row within tile (S^T output col)
  const int kg = lane >> 4;   // lane group 0..3

  // XCD-aware bijective swizzle (2048 WGs, 8 XCDs -> 2 whole batches per XCD)
  const int bid = blockIdx.x;
  const int swz = (bid & 7) * ((NB * (NL / QT)) / 8) + (bid >> 3);
  const int b = swz >> 7;               // 128 q-tiles per batch
  const int q0 = (swz & 127) * QT;
  const int cbase = w * SLICE;
  const size_t mrow0 = ((size_t)b * NL + q0) * NL;
  const size_t lrow = mrow0 + (size_t)fr * NL + (size_t)(cbase + 4 * kg);

  // Q fragments (temperature folded in)
  bf16x8 a0, a1;
  if constexpr (WS) {
    const u16* qp = qs + ((size_t)(b * NL + q0 + fr)) * ND + kg * 8;
    a0 = *(const bf16x8*)qp;
    a1 = *(const bf16x8*)(qp + 32);
  } else {
    const float* qp = q + ((size_t)(b * NL + q0 + fr)) * ND + kg * 8;
#pragma unroll
    for (int i = 0; i < 8; ++i) {
      a0[i] = (short)f2bf(qp[i] * 0.125f);
      a1[i] = (short)f2bf(qp[i + 32] * 0.125f);
    }
  }

  // ---- Phase A: hoisted mask loads, then S = QK^T -> exp kept in regs ----
  uint32_t nibs[NT];   // all mask nibbles up-front (independent loads, deep MLP)
#pragma unroll
  for (int ti = 0; ti < NT; ++ti)
    nibs[ti] = mnib<MODE>(mask, lrow + (size_t)(ti * 16));

  uint32_t epk[2 * NT];   // 32 regs: bf16-packed e, fully static indexing
  float rs = 0.f;
#pragma unroll
  for (int ti = 0; ti < NT; ++ti) {
    const int c0 = cbase + ti * 16;
    bf16x8 b0, b1;
    loadKfrag<WS>(k, kb, b, c0 + fr, kg, b0, b1);
    f32x4 s = {0.f, 0.f, 0.f, 0.f};
    s = MFMA(b0, a0, s, 0, 0, 0);   // S^T: lane holds S[q=fr][k=c0+4kg+j]
    s = MFMA(b1, a1, s, 0, 0, 0);
    const uint32_t nib = nibs[ti];
    const float e0 = (nib & 1u) ? 0.f : __expf(s[0]);
    const float e1 = (nib & 2u) ? 0.f : __expf(s[1]);
    const float e2 = (nib & 4u) ? 0.f : __expf(s[2]);
    const float e3 = (nib & 8u) ? 0.f : __expf(s[3]);
    rs += (e0 + e1) + (e2 + e3);
    epk[2 * ti]     = (uint32_t)f2bf(e0) | ((uint32_t)f2bf(e1) << 16);
    epk[2 * ti + 1] = (uint32_t)f2bf(e2) | ((uint32_t)f2bf(e3) << 16);
  }
  rs += __shfl_xor(rs, 16, 64);
  rs += __shfl_xor(rs, 32, 64);
  if (lane < 16) rsums[w * QT + fr] = rs;
  __syncthreads();
  float inv = 0.f;
#pragma unroll
  for (int ww = 0; ww < NW; ++ww) inv += rsums[ww * QT + fr];
  inv = 1.0f / inv;

  // ---- Phase B1: streaming in 2 batches of 8 (forces 8 loads in flight) ----
  const float* ewp = ew + lrow;
  float* atp = attn + lrow;
#pragma unroll
  for (int bb = 0; bb < 2; ++bb) {
    f32x4 w4[8];
#pragma unroll
    for (int u = 0; u < 8; ++u)
      w4[u] = __builtin_nontemporal_load((const f32x4*)(ewp + (bb * 8 + u) * 16));
#pragma unroll
    for (int u = 0; u < 8; ++u) {
      const int sg = bb * 8 + u;
      f32x4 p;
      p[0] = bflo2f(epk[2 * sg])     * inv * w4[u][0];
      p[1] = bfhi2f(epk[2 * sg])     * inv * w4[u][1];
      p[2] = bflo2f(epk[2 * sg + 1]) * inv * w4[u][2];
      p[3] = bfhi2f(epk[2 * sg + 1]) * inv * w4[u][3];
      __builtin_nontemporal_store(p, (f32x4*)(atp + sg * 16));
      epk[2 * sg]     = (uint32_t)f2bf(p[0]) | ((uint32_t)f2bf(p[1]) << 16);
      epk[2 * sg + 1] = (uint32_t)f2bf(p[2]) | ((uint32_t)f2bf(p[3]) << 16);
    }
  }

  // ---- Phase B2: register-only P transpose via shuffles + PV MFMA ----
  // lane (kg,fr) needs P[q=fr][k = 32gi + 8kg + 0..7]:
  //   tile = 2gi + (kg>>1); chunks m=2(kg&1), 2(kg&1)+1 -> src lanes fr+16m, fr+16m+16
  const int sA = fr + 16 * (2 * (kg & 1));
  const int sB = sA + 16;
  const bool tb = (kg >= 2);
  f32x4 oA[4] = {{0.f,0.f,0.f,0.f},{0.f,0.f,0.f,0.f},{0.f,0.f,0.f,0.f},{0.f,0.f,0.f,0.f}};
#pragma unroll
  for (int gi = 0; gi < NT / 2; ++gi) {
    const uint32_t x0 = (uint32_t)__shfl((int)epk[4 * gi],     sA, 64);
    const uint32_t x1 = (uint32_t)__shfl((int)epk[4 * gi + 1], sA, 64);
    const uint32_t x2 = (uint32_t)__shfl((int)epk[4 * gi],     sB, 64);
    const uint32_t x3 = (uint32_t)__shfl((int)epk[4 * gi + 1], sB, 64);
    const uint32_t y0 = (uint32_t)__shfl((int)epk[4 * gi + 2], sA, 64);
    const uint32_t y1 = (uint32_t)__shfl((int)epk[4 * gi + 3], sA, 64);
    const uint32_t y2 = (uint32_t)__shfl((int)epk[4 * gi + 2], sB, 64);
    const uint32_t y3 = (uint32_t)__shfl((int)epk[4 * gi + 3], sB, 64);
    union { uint32_t wd[4]; bf16x8 v; } pu;
    pu.wd[0] = tb ? y0 : x0;
    pu.wd[1] = tb ? y1 : x1;
    pu.wd[2] = tb ? y2 : x2;
    pu.wd[3] = tb ? y3 : x3;
    const bf16x8 pa = pu.v;
    const int kk = cbase + gi * 32 + kg * 8;
    if constexpr (WS) {
      const u16* vp = vt + ((size_t)(b * ND + fr)) * NL + kk;   // VT[d][k]
      oA[0] = MFMA(pa, *(const bf16x8*)(vp),           oA[0], 0, 0, 0);
      oA[1] = MFMA(pa, *(const bf16x8*)(vp + 16 * NL), oA[1], 0, 0, 0);
      oA[2] = MFMA(pa, *(const bf16x8*)(vp + 32 * NL), oA[2], 0, 0, 0);
      oA[3] = MFMA(pa, *(const bf16x8*)(vp + 48 * NL), oA[3], 0, 0, 0);
    } else {
#pragma unroll
      for (int dt = 0; dt < 4; ++dt) {
        bf16x8 vf;
#pragma unroll
        for (int i = 0; i < 8; ++i)
          vf[i] = (short)f2bf(v[((size_t)(b * NL + kk + i)) * ND + dt * 16 + fr]);
        oA[dt] = MFMA(pa, vf, oA[dt], 0, 0, 0);
      }
    }
  }

  // ---- 4-round staged cross-wave out reduction (8 KB LDS, 2 waves/round) ----
  f32x4 acc = {0.f, 0.f, 0.f, 0.f};
  const int r = tid >> 4;            // valid for tid < 256
  const int d4 = (tid & 15) * 4;
#pragma unroll
  for (int round = 0; round < NW / 2; ++round) {
    if ((w >> 1) == round) {
      float* od = osta + (w & 1) * (QT * ND);
#pragma unroll
      for (int dt = 0; dt < 4; ++dt)
#pragma unroll
        for (int j = 0; j < 4; ++j)
          od[(4 * kg + j) * ND + dt * 16 + fr] = oA[dt][j];
    }
    __syncthreads();
    if (tid < QT * ND / 4) {
      acc += *(const f32x4*)(osta + r * ND + d4) +
             *(const f32x4*)(osta + QT * ND + r * ND + d4);
    }
    __syncthreads();
  }
  if (tid < QT * ND / 4)
    *(f32x4*)(out + ((size_t)(b * NL + q0 + r)) * ND + d4) = acc;
}

template <bool WS>
__global__ void __launch_bounds__(NTHREADS, 4)   // 4 waves/EU min -> 2 WGs/CU, VGPR<=128
attn_main(const float* __restrict__ q, const float* __restrict__ k,
          const float* __restrict__ v, const float* __restrict__ ew,
          const void* __restrict__ mask,
          const u16* __restrict__ qs, const u16* __restrict__ kb,
          const u16* __restrict__ vt,
          float* __restrict__ out, float* __restrict__ attn) {
  __shared__ float osta[2 * QT * ND];   // 8 KB: 2-wave staging, 4 rounds
  __shared__ float rsums[NW * QT];
  __shared__ int s_mode;
  if (threadIdx.x < 64) {
    const uint32_t x = ((const uint32_t*)mask)[threadIdx.x];
    const int all01 = __all(x <= 1u);
    const int allf  = __all(x == 0u || x == 0x3F800000u);
    const int oddz  = __all(((threadIdx.x & 1) == 0) || (x == 0u));
    if (threadIdx.x == 0) s_mode = all01 ? (oddz ? 3 : 0) : (allf ? 2 : 1);
  }
  __syncthreads();
  switch (s_mode) {
    case 0:  attn_body<0, WS>(q, k, v, ew, mask, qs, kb, vt, out, attn, osta, rsums); break;
    case 1:  attn_body<1, WS>(q, k, v, ew, mask, qs, kb, vt, out, attn, osta, rsums); break;
    case 2:  attn_body<2, WS>(q, k, v, ew, mask, qs, kb, vt, out, attn, osta, rsums); break;
    default: attn_body<3, WS>(q, k, v, ew, mask, qs, kb, vt, out, attn, osta, rsums); break;
  }
}

// prep: q*0.125 -> bf16 qs ; k -> bf16 kb   (f32x4 per thread)
__global__ void __launch_bounds__(256)
prep_qk(const float* __restrict__ q, const float* __restrict__ k,
        u16* __restrict__ qs, u16* __restrict__ kb) {
  const size_t NQ4 = (size_t)NB * NL * ND / 4;
  const size_t i = (size_t)blockIdx.x * 256 + threadIdx.x;
  f32x4 val;
  u16* dst;
  if (i < NQ4) {
    val = ((const f32x4*)q)[i];
    val *= 0.125f;
    dst = qs + i * 4;
  } else {
    val = ((const f32x4*)k)[i - NQ4];
    dst = kb + (i - NQ4) * 4;
  }
  u16x4 o;
#pragma unroll
  for (int j = 0; j < 4; ++j) o[j] = f2bf(val[j]);
  *(u16x4*)dst = o;
}

// prep: v -> bf16 V^T (per-batch 64x2048), LDS tile transpose
__global__ void __launch_bounds__(256)
prep_vt(const float* __restrict__ v, u16* __restrict__ vt) {
  __shared__ float t[64 * 68];
  const int b = blockIdx.y;
  const int k0 = blockIdx.x * 64;
  const int tid = threadIdx.x;
  const int rr = tid >> 4;
  const int c4 = (tid & 15) * 4;
#pragma unroll
  for (int i = 0; i < 4; ++i) {
    const int r = rr + 16 * i;
    const f32x4 val = *(const f32x4*)(v + ((size_t)(b * NL + k0 + r)) * ND + c4);
    *(f32x4*)(t + r * 68 + c4) = val;
  }
  __syncthreads();
#pragma unroll
  for (int i = 0; i < 4; ++i) {
    const int d = rr + 16 * i;
    u16x4 o;
#pragma unroll
    for (int j = 0; j < 4; ++j) o[j] = f2bf(t[(c4 + j) * 68 + d]);
    *(u16x4*)(vt + ((size_t)(b * ND + d)) * NL + k0 + c4) = o;
  }
}

extern "C" void kernel_launch(void* const* d_in, const int* in_sizes, int n_in,
                              void* d_out, int out_size, void* d_ws, size_t ws_size,
                              hipStream_t stream) {
  const float* q    = (const float*)d_in[0];
  const float* k    = (const float*)d_in[1];
  const float* v    = (const float*)d_in[2];
  const float* ew   = (const float*)d_in[3];
  const void*  mask = d_in[4];
  float* out  = (float*)d_out;
  float* attn = out + (size_t)NB * NL * ND;

  const size_t QE = (size_t)NB * NL * ND;   // 2M elements per matrix
  u16* qs = (u16*)d_ws;
  u16* kb = qs + QE;
  u16* vt = kb + QE;

  dim3 grid(NB * (NL / QT));   // 2048, 1-D for XCD swizzle
  if (ws_size >= 3 * QE * sizeof(u16)) {
    prep_qk<<<dim3((unsigned)(2 * QE / 4 / 256)), 256, 0, stream>>>(q, k, qs, kb);
    prep_vt<<<dim3(NL / 64, NB), 256, 0, stream>>>(v, vt);
    attn_main<true><<<grid, NTHREADS, 0, stream>>>(q, k, v, ew, mask, qs, kb, vt, out, attn);
  } else {
    attn_main<false><<<grid, NTHREADS, 0, stream>>>(q, k, v, ew, mask, nullptr, nullptr, nullptr, out, attn);
  }
}

// Round 11
// 255.040 us; speedup vs baseline: 1.1972x; 1.1917x over previous
//
#include <hip/hip_runtime.h>
#include <cstdint>
#include <cstddef>

#define NB 16
#define NL 2048
#define ND 64
#define QT 16                 // q rows per workgroup
#define NW 8                  // waves per workgroup
#define NTHREADS (NW * 64)
#define SLICE (NL / NW)       // 256 k-cols per wave
#define NT (SLICE / 16)       // 16 MFMA col-tiles per wave
#define ROWU 1026             // u32 per padded LDS row (4104 B)
#define ELSU (QT * ROWU)      // 16416 u32 = 65664 B
#define LDSB (ELSU * 4)

typedef __attribute__((ext_vector_type(8))) short bf16x8;
typedef __attribute__((ext_vector_type(4))) float f32x4;
typedef __attribute__((ext_vector_type(4))) int i32x4;
typedef __attribute__((ext_vector_type(4))) unsigned short u16x4;
typedef __attribute__((ext_vector_type(2))) unsigned int u32x2;
typedef __attribute__((ext_vector_type(4))) unsigned int u32x4;
typedef unsigned short u16;

#define MFMA __builtin_amdgcn_mfma_f32_16x16x32_bf16

__device__ __forceinline__ u16 f2bf(float x) {
  union { float f; uint32_t u; } v; v.f = x;
  uint32_t r = v.u + 0x7FFFu + ((v.u >> 16) & 1u);   // RNE
  return (u16)(r >> 16);
}
__device__ __forceinline__ float bfhi2f(uint32_t w) {
  union { uint32_t u; float f; } v; v.u = w & 0xFFFF0000u; return v.f;
}
__device__ __forceinline__ float bflo2f(uint32_t w) {
  union { uint32_t u; float f; } v; v.u = w << 16; return v.f;
}
// XOR-swizzle byte offset within a 4096B LDS row (keeps 16B alignment)
__device__ __forceinline__ int swzb(int cb) { return cb ^ (((cb >> 7) & 7) << 4); }

// mask nibble (fallback path). MODE: 0=i32,1=u8,2=f32,3=i64
template <int MODE>
__device__ __forceinline__ uint32_t mnib(const void* __restrict__ m, size_t i) {
  if constexpr (MODE == 1) {
    const uint32_t x = __builtin_nontemporal_load((const uint32_t*)((const uint8_t*)m + i));
    return (x | (x >> 7) | (x >> 14) | (x >> 21)) & 0xFu;
  } else if constexpr (MODE == 0) {
    const i32x4 x = __builtin_nontemporal_load(((const i32x4*)((const int*)m + i)));
    return (uint32_t)(x[0] != 0) | ((uint32_t)(x[1] != 0) << 1) |
           ((uint32_t)(x[2] != 0) << 2) | ((uint32_t)(x[3] != 0) << 3);
  } else if constexpr (MODE == 2) {
    const f32x4 x = __builtin_nontemporal_load(((const f32x4*)((const float*)m + i)));
    return (uint32_t)(x[0] != 0.f) | ((uint32_t)(x[1] != 0.f) << 1) |
           ((uint32_t)(x[2] != 0.f) << 2) | ((uint32_t)(x[3] != 0.f) << 3);
  } else {
    const uint32_t* p = (const uint32_t*)m + 2 * i;
    return (uint32_t)(p[0] != 0u) | ((uint32_t)(p[2] != 0u) << 1) |
           ((uint32_t)(p[4] != 0u) << 2) | ((uint32_t)(p[6] != 0u) << 3);
  }
}

template <bool WS>
__device__ __forceinline__ void loadKfrag(const float* __restrict__ k,
                                          const u16* __restrict__ kb,
                                          int b, int row, int kg,
                                          bf16x8& b0, bf16x8& b1) {
  if constexpr (WS) {
    const u16* kp = kb + ((size_t)(b * NL + row)) * ND + kg * 8;
    b0 = *(const bf16x8*)kp;
    b1 = *(const bf16x8*)(kp + 32);
  } else {
    const float* kp = k + ((size_t)(b * NL + row)) * ND + kg * 8;
#pragma unroll
    for (int i = 0; i < 8; ++i) {
      b0[i] = (short)f2bf(kp[i]);
      b1[i] = (short)f2bf(kp[i + 32]);
    }
  }
}

template <int MMODE, bool WS>
__device__ __forceinline__ void attn_core(
    const float* __restrict__ q, const float* __restrict__ k,
    const float* __restrict__ v, const float* __restrict__ ew,
    const void* __restrict__ mask,
    const u16* __restrict__ qs, const u16* __restrict__ kb,
    const u16* __restrict__ vt, const uint32_t* __restrict__ mb,
    float* __restrict__ out, float* __restrict__ attn,
    uint32_t* __restrict__ els, float* __restrict__ rsums) {
  const int tid = threadIdx.x;
  const int lane = tid & 63;
  const int w = tid >> 6;
  const int fr = lane & 15;
  const int kg = lane >> 4;

  // XCD-aware bijective swizzle
  const int bid = blockIdx.x;
  const int swzid = (bid & 7) * ((NB * (NL / QT)) / 8) + (bid >> 3);
  const int b = swzid >> 7;
  const int q0 = (swzid & 127) * QT;
  const int cbase = w * SLICE;
  const size_t bq = (size_t)b * NL + q0;
  const size_t mrow0 = bq * NL;
  const size_t lrow = mrow0 + (size_t)fr * NL + (size_t)(cbase + 4 * kg);

  // Q fragments (temperature folded in)
  bf16x8 a0, a1;
  if constexpr (WS) {
    const u16* qp = qs + (bq + fr) * ND + kg * 8;
    a0 = *(const bf16x8*)qp;
    a1 = *(const bf16x8*)(qp + 32);
  } else {
    const float* qp = q + (bq + fr) * ND + kg * 8;
#pragma unroll
    for (int i = 0; i < 8; ++i) {
      a0[i] = (short)f2bf(qp[i] * 0.125f);
      a1[i] = (short)f2bf(qp[i + 32] * 0.125f);
    }
  }

  // mask bit-words for this lane's (row fr, 256-col slice)
  uint32_t mw[8];
  if constexpr (WS) {
    const uint32_t* mbr = mb + (bq + fr) * (NL / 32) + (cbase >> 5);
#pragma unroll
    for (int u = 0; u < 8; ++u) mw[u] = mbr[u];
  }

  // ---- Phase A: S^T = mfma(K,Q); e = exp(masked S) -> swizzled LDS tile ----
  float rs = 0.f;
#pragma unroll
  for (int ti = 0; ti < NT; ++ti) {
    const int c0 = cbase + ti * 16;
    bf16x8 b0, b1;
    loadKfrag<WS>(k, kb, b, c0 + fr, kg, b0, b1);
    f32x4 s = {0.f, 0.f, 0.f, 0.f};
    s = MFMA(b0, a0, s, 0, 0, 0);   // lane holds S[q=fr][k=c0+4kg+j]
    s = MFMA(b1, a1, s, 0, 0, 0);
    uint32_t nib;
    if constexpr (WS) nib = (mw[ti >> 1] >> (16 * (ti & 1) + 4 * kg)) & 0xFu;
    else              nib = mnib<MMODE>(mask, lrow + (size_t)(ti * 16));
    const float e0 = (nib & 1u) ? 0.f : __expf(s[0]);
    const float e1 = (nib & 2u) ? 0.f : __expf(s[1]);
    const float e2 = (nib & 4u) ? 0.f : __expf(s[2]);
    const float e3 = (nib & 8u) ? 0.f : __expf(s[3]);
    rs += (e0 + e1) + (e2 + e3);
    u32x2 ep;
    ep[0] = (uint32_t)f2bf(e0) | ((uint32_t)f2bf(e1) << 16);
    ep[1] = (uint32_t)f2bf(e2) | ((uint32_t)f2bf(e3) << 16);
    *(u32x2*)(els + fr * ROWU + (swzb((c0 + 4 * kg) * 2) >> 2)) = ep;
  }
  rs += __shfl_xor(rs, 16, 64);
  rs += __shfl_xor(rs, 32, 64);
  if (lane < 16) rsums[w * QT + fr] = rs;
  __syncthreads();

  // ---- Phase B1: row-contiguous streaming (1 KB/wave-instr on ew & attn) ----
  // wave w owns rows 2w, 2w+1; lane l covers cols 256*s + 4l
#pragma unroll
  for (int half = 0; half < 2; ++half) {
    const int rr = 2 * w + half;
    float inv = 0.f;
#pragma unroll
    for (int ww = 0; ww < NW; ++ww) inv += rsums[ww * QT + rr];
    inv = 1.0f / inv;
    const size_t gb = (bq + rr) * NL + 4 * lane;
    const float* ewp = ew + gb;
    float* atp = attn + gb;
    uint32_t* lrp = els + rr * ROWU;
    f32x4 w4[8];
    u32x2 el8[8];
#pragma unroll
    for (int s2 = 0; s2 < 8; ++s2)
      w4[s2] = __builtin_nontemporal_load((const f32x4*)(ewp + 256 * s2));
#pragma unroll
    for (int s2 = 0; s2 < 8; ++s2)
      el8[s2] = *(const u32x2*)(lrp + (swzb(512 * s2 + 8 * lane) >> 2));
#pragma unroll
    for (int s2 = 0; s2 < 8; ++s2) {
      f32x4 p;
      p[0] = bflo2f(el8[s2][0]) * inv * w4[s2][0];
      p[1] = bfhi2f(el8[s2][0]) * inv * w4[s2][1];
      p[2] = bflo2f(el8[s2][1]) * inv * w4[s2][2];
      p[3] = bfhi2f(el8[s2][1]) * inv * w4[s2][3];
      __builtin_nontemporal_store(p, (f32x4*)(atp + 256 * s2));
      u32x2 pp;
      pp[0] = (uint32_t)f2bf(p[0]) | ((uint32_t)f2bf(p[1]) << 16);
      pp[1] = (uint32_t)f2bf(p[2]) | ((uint32_t)f2bf(p[3]) << 16);
      *(u32x2*)(lrp + (swzb(512 * s2 + 8 * lane) >> 2)) = pp;
    }
  }
  __syncthreads();

  // ---- Phase B2: PV MFMA, P A-fragments straight from LDS ----
  f32x4 oA[4] = {{0.f,0.f,0.f,0.f},{0.f,0.f,0.f,0.f},{0.f,0.f,0.f,0.f},{0.f,0.f,0.f,0.f}};
#pragma unroll
  for (int gi = 0; gi < NT / 2; ++gi) {
    union { u32x4 u; bf16x8 v8; } pu;
    pu.u = *(const u32x4*)(els + fr * ROWU + (swzb((cbase + 32 * gi + 8 * kg) * 2) >> 2));
    const bf16x8 pa = pu.v8;
    const int kk = cbase + gi * 32 + kg * 8;
    if constexpr (WS) {
      const u16* vp = vt + ((size_t)(b * ND + fr)) * NL + kk;   // VT[d][k]
      oA[0] = MFMA(pa, *(const bf16x8*)(vp),           oA[0], 0, 0, 0);
      oA[1] = MFMA(pa, *(const bf16x8*)(vp + 16 * NL), oA[1], 0, 0, 0);
      oA[2] = MFMA(pa, *(const bf16x8*)(vp + 32 * NL), oA[2], 0, 0, 0);
      oA[3] = MFMA(pa, *(const bf16x8*)(vp + 48 * NL), oA[3], 0, 0, 0);
    } else {
#pragma unroll
      for (int dt = 0; dt < 4; ++dt) {
        bf16x8 vf;
#pragma unroll
        for (int i = 0; i < 8; ++i)
          vf[i] = (short)f2bf(v[((size_t)(b * NL + kk + i)) * ND + dt * 16 + fr]);
        oA[dt] = MFMA(pa, vf, oA[dt], 0, 0, 0);
      }
    }
  }
  __syncthreads();   // els reads done; safe to reuse as out-staging

  // ---- 4-round staged cross-wave out reduction (osta aliases els) ----
  float* osta = (float*)els;
  f32x4 acc = {0.f, 0.f, 0.f, 0.f};
  const int rrr = tid >> 4;
  const int d4 = (tid & 15) * 4;
#pragma unroll
  for (int round = 0; round < NW / 2; ++round) {
    if ((w >> 1) == round) {
      float* od = osta + (w & 1) * (QT * ND);
#pragma unroll
      for (int dt = 0; dt < 4; ++dt)
#pragma unroll
        for (int j = 0; j < 4; ++j)
          od[(4 * kg + j) * ND + dt * 16 + fr] = oA[dt][j];
    }
    __syncthreads();
    if (tid < QT * ND / 4) {
      acc += *(const f32x4*)(osta + rrr * ND + d4) +
             *(const f32x4*)(osta + QT * ND + rrr * ND + d4);
    }
    __syncthreads();
  }
  if (tid < QT * ND / 4)
    *(f32x4*)(out + (bq + rrr) * ND + d4) = acc;
}

__global__ void __launch_bounds__(NTHREADS, 4)
attn_ws(const float* __restrict__ q, const float* __restrict__ k,
        const float* __restrict__ v, const float* __restrict__ ew,
        const u16* __restrict__ qs, const u16* __restrict__ kb,
        const u16* __restrict__ vt, const uint32_t* __restrict__ mb,
        float* __restrict__ out, float* __restrict__ attn) {
  extern __shared__ uint32_t els[];
  __shared__ float rsums[NW * QT];
  attn_core<0, true>(q, k, v, ew, nullptr, qs, kb, vt, mb, out, attn, els, rsums);
}

__global__ void __launch_bounds__(NTHREADS, 4)
attn_fb(const float* __restrict__ q, const float* __restrict__ k,
        const float* __restrict__ v, const float* __restrict__ ew,
        const void* __restrict__ mask,
        float* __restrict__ out, float* __restrict__ attn) {
  extern __shared__ uint32_t els[];
  __shared__ float rsums[NW * QT];
  __shared__ int s_mode;
  if (threadIdx.x < 64) {
    const uint32_t x = ((const uint32_t*)mask)[threadIdx.x];
    const int all01 = __all(x <= 1u);
    const int allf  = __all(x == 0u || x == 0x3F800000u);
    const int oddz  = __all(((threadIdx.x & 1) == 0) || (x == 0u));
    if (threadIdx.x == 0) s_mode = all01 ? (oddz ? 3 : 0) : (allf ? 2 : 1);
  }
  __syncthreads();
  switch (s_mode) {
    case 0:  attn_core<0, false>(q, k, v, ew, mask, nullptr, nullptr, nullptr, nullptr, out, attn, els, rsums); break;
    case 1:  attn_core<1, false>(q, k, v, ew, mask, nullptr, nullptr, nullptr, nullptr, out, attn, els, rsums); break;
    case 2:  attn_core<2, false>(q, k, v, ew, mask, nullptr, nullptr, nullptr, nullptr, out, attn, els, rsums); break;
    default: attn_core<3, false>(q, k, v, ew, mask, nullptr, nullptr, nullptr, nullptr, out, attn, els, rsums); break;
  }
}

// prep: q*0.125 -> bf16 qs ; k -> bf16 kb
__global__ void __launch_bounds__(256)
prep_qk(const float* __restrict__ q, const float* __restrict__ k,
        u16* __restrict__ qs, u16* __restrict__ kb) {
  const size_t NQ4 = (size_t)NB * NL * ND / 4;
  const size_t i = (size_t)blockIdx.x * 256 + threadIdx.x;
  f32x4 val;
  u16* dst;
  if (i < NQ4) {
    val = ((const f32x4*)q)[i];
    val *= 0.125f;
    dst = qs + i * 4;
  } else {
    val = ((const f32x4*)k)[i - NQ4];
    dst = kb + (i - NQ4) * 4;
  }
  u16x4 o;
#pragma unroll
  for (int j = 0; j < 4; ++j) o[j] = f2bf(val[j]);
  *(u16x4*)dst = o;
}

// prep: v -> bf16 V^T (per-batch 64x2048)
__global__ void __launch_bounds__(256)
prep_vt(const float* __restrict__ v, u16* __restrict__ vt) {
  __shared__ float t[64 * 68];
  const int b = blockIdx.y;
  const int k0 = blockIdx.x * 64;
  const int tid = threadIdx.x;
  const int rr = tid >> 4;
  const int c4 = (tid & 15) * 4;
#pragma unroll
  for (int i = 0; i < 4; ++i) {
    const int r = rr + 16 * i;
    const f32x4 val = *(const f32x4*)(v + ((size_t)(b * NL + k0 + r)) * ND + c4);
    *(f32x4*)(t + r * 68 + c4) = val;
  }
  __syncthreads();
#pragma unroll
  for (int i = 0; i < 4; ++i) {
    const int d = rr + 16 * i;
    u16x4 o;
#pragma unroll
    for (int j = 0; j < 4; ++j) o[j] = f2bf(t[(c4 + j) * 68 + d]);
    *(u16x4*)(vt + ((size_t)(b * ND + d)) * NL + k0 + c4) = o;
  }
}

// prep: pack mask -> 1 bit/element (u32 covers 32 consecutive k of one row)
__global__ void __launch_bounds__(256)
prep_mask(const void* __restrict__ mask, uint32_t* __restrict__ mb) {
  __shared__ int pm;
  if (threadIdx.x < 64) {
    const uint32_t x = ((const uint32_t*)mask)[threadIdx.x];
    const int all01 = __all(x <= 1u);
    const int allf  = __all(x == 0u || x == 0x3F800000u);
    const int oddz  = __all(((threadIdx.x & 1) == 0) || (x == 0u));
    if (threadIdx.x == 0) pm = all01 ? (oddz ? 3 : 0) : (allf ? 2 : 1);
  }
  __syncthreads();
  const int mode = pm;
  const size_t t = (size_t)blockIdx.x * 256 + threadIdx.x;
  uint32_t bits = 0;
  if (mode == 1) {
    const u32x4 x0 = *(((const u32x4*)mask) + t * 2);
    const u32x4 x1 = *(((const u32x4*)mask) + t * 2 + 1);
#pragma unroll
    for (int i = 0; i < 4; ++i)
#pragma unroll
      for (int by = 0; by < 4; ++by) {
        bits |= (((x0[i] >> (8 * by)) & 0xFFu) ? 1u : 0u) << (i * 4 + by);
        bits |= (((x1[i] >> (8 * by)) & 0xFFu) ? 1u : 0u) << (16 + i * 4 + by);
      }
  } else if (mode == 0 || mode == 2) {
#pragma unroll
    for (int c = 0; c < 8; ++c) {
      const u32x4 x = *(((const u32x4*)mask) + t * 8 + c);
#pragma unroll
      for (int i = 0; i < 4; ++i) bits |= (x[i] ? 1u : 0u) << (c * 4 + i);
    }
  } else {
    const uint32_t* p = (const uint32_t*)mask;
#pragma unroll
    for (int i = 0; i < 32; ++i) bits |= (p[2 * (t * 32 + i)] ? 1u : 0u) << i;
  }
  mb[t] = bits;
}

extern "C" void kernel_launch(void* const* d_in, const int* in_sizes, int n_in,
                              void* d_out, int out_size, void* d_ws, size_t ws_size,
                              hipStream_t stream) {
  const float* q    = (const float*)d_in[0];
  const float* k    = (const float*)d_in[1];
  const float* v    = (const float*)d_in[2];
  const float* ew   = (const float*)d_in[3];
  const void*  mask = d_in[4];
  float* out  = (float*)d_out;
  float* attn = out + (size_t)NB * NL * ND;

  const size_t QE = (size_t)NB * NL * ND;           // 2M elems per matrix
  const size_t MBW = (size_t)NB * NL * (NL / 32);   // 2M mask words
  u16* qs = (u16*)d_ws;
  u16* kb = qs + QE;
  u16* vt = kb + QE;
  uint32_t* mb = (uint32_t*)(vt + QE);

  (void)hipFuncSetAttribute(reinterpret_cast<const void*>(attn_ws),
                            hipFuncAttributeMaxDynamicSharedMemorySize, LDSB);
  (void)hipFuncSetAttribute(reinterpret_cast<const void*>(attn_fb),
                            hipFuncAttributeMaxDynamicSharedMemorySize, LDSB);

  dim3 grid(NB * (NL / QT));   // 2048, 1-D for XCD swizzle
  if (ws_size >= 3 * QE * sizeof(u16) + MBW * sizeof(uint32_t)) {
    prep_qk<<<dim3((unsigned)(2 * QE / 4 / 256)), 256, 0, stream>>>(q, k, qs, kb);
    prep_vt<<<dim3(NL / 64, NB), 256, 0, stream>>>(v, vt);
    prep_mask<<<dim3((unsigned)(MBW / 256)), 256, 0, stream>>>(mask, mb);
    attn_ws<<<grid, NTHREADS, LDSB, stream>>>(q, k, v, ew, qs, kb, vt, mb, out, attn);
  } else {
    attn_fb<<<grid, NTHREADS, LDSB, stream>>>(q, k, v, ew, mask, out, attn);
  }
}

// Round 12
// 246.613 us; speedup vs baseline: 1.2381x; 1.0342x over previous
//
#include <hip/hip_runtime.h>
#include <cstdint>
#include <cstddef>

#define NB 16
#define NL 2048
#define ND 64
#define QT 16                 // q rows per workgroup
#define NW 8                  // waves per workgroup
#define NTHREADS (NW * 64)
#define SLICE (NL / NW)       // 256 k-cols per wave
#define NT (SLICE / 16)       // 16 MFMA col-tiles per wave
#define ROWU 1026             // u32 per padded LDS row (4104 B)
#define ELSU (QT * ROWU)      // 16416 u32 = 65664 B
#define LDSB (ELSU * 4)

typedef __attribute__((ext_vector_type(8))) short bf16x8;
typedef __attribute__((ext_vector_type(4))) float f32x4;
typedef __attribute__((ext_vector_type(4))) int i32x4;
typedef __attribute__((ext_vector_type(4))) unsigned short u16x4;
typedef __attribute__((ext_vector_type(2))) unsigned int u32x2;
typedef __attribute__((ext_vector_type(4))) unsigned int u32x4;
typedef unsigned short u16;

#define MFMA __builtin_amdgcn_mfma_f32_16x16x32_bf16

__device__ __forceinline__ u16 f2bf(float x) {
  union { float f; uint32_t u; } v; v.f = x;
  uint32_t r = v.u + 0x7FFFu + ((v.u >> 16) & 1u);   // RNE
  return (u16)(r >> 16);
}
__device__ __forceinline__ float bfhi2f(uint32_t w) {
  union { uint32_t u; float f; } v; v.u = w & 0xFFFF0000u; return v.f;
}
__device__ __forceinline__ float bflo2f(uint32_t w) {
  union { uint32_t u; float f; } v; v.u = w << 16; return v.f;
}
// XOR-swizzle byte offset within a 4096B LDS row (keeps 16B alignment)
__device__ __forceinline__ int swzb(int cb) { return cb ^ (((cb >> 7) & 7) << 4); }

// mask nibble (fallback path). MODE: 0=i32,1=u8,2=f32,3=i64
template <int MODE>
__device__ __forceinline__ uint32_t mnib(const void* __restrict__ m, size_t i) {
  if constexpr (MODE == 1) {
    const uint32_t x = __builtin_nontemporal_load((const uint32_t*)((const uint8_t*)m + i));
    return (x | (x >> 7) | (x >> 14) | (x >> 21)) & 0xFu;
  } else if constexpr (MODE == 0) {
    const i32x4 x = __builtin_nontemporal_load(((const i32x4*)((const int*)m + i)));
    return (uint32_t)(x[0] != 0) | ((uint32_t)(x[1] != 0) << 1) |
           ((uint32_t)(x[2] != 0) << 2) | ((uint32_t)(x[3] != 0) << 3);
  } else if constexpr (MODE == 2) {
    const f32x4 x = __builtin_nontemporal_load(((const f32x4*)((const float*)m + i)));
    return (uint32_t)(x[0] != 0.f) | ((uint32_t)(x[1] != 0.f) << 1) |
           ((uint32_t)(x[2] != 0.f) << 2) | ((uint32_t)(x[3] != 0.f) << 3);
  } else {
    const uint32_t* p = (const uint32_t*)m + 2 * i;
    return (uint32_t)(p[0] != 0u) | ((uint32_t)(p[2] != 0u) << 1) |
           ((uint32_t)(p[4] != 0u) << 2) | ((uint32_t)(p[6] != 0u) << 3);
  }
}

template <bool WS>
__device__ __forceinline__ void loadKfrag(const float* __restrict__ k,
                                          const u16* __restrict__ kb,
                                          int b, int row, int kg,
                                          bf16x8& b0, bf16x8& b1) {
  if constexpr (WS) {
    const u16* kp = kb + ((size_t)(b * NL + row)) * ND + kg * 8;
    b0 = *(const bf16x8*)kp;
    b1 = *(const bf16x8*)(kp + 32);
  } else {
    const float* kp = k + ((size_t)(b * NL + row)) * ND + kg * 8;
#pragma unroll
    for (int i = 0; i < 8; ++i) {
      b0[i] = (short)f2bf(kp[i]);
      b1[i] = (short)f2bf(kp[i + 32]);
    }
  }
}

template <int MMODE, bool WS>
__device__ __forceinline__ void attn_core(
    const float* __restrict__ q, const float* __restrict__ k,
    const float* __restrict__ v, const float* __restrict__ ew,
    const void* __restrict__ mask,
    const u16* __restrict__ qs, const u16* __restrict__ kb,
    const u16* __restrict__ vt, const uint32_t* __restrict__ mb,
    float* __restrict__ out, float* __restrict__ attn,
    uint32_t* __restrict__ els, float* __restrict__ rsums) {
  const int tid = threadIdx.x;
  const int lane = tid & 63;
  const int w = tid >> 6;
  const int fr = lane & 15;
  const int kg = lane >> 4;

  // XCD-aware bijective swizzle
  const int bid = blockIdx.x;
  const int swzid = (bid & 7) * ((NB * (NL / QT)) / 8) + (bid >> 3);
  const int b = swzid >> 7;
  const int q0 = (swzid & 127) * QT;
  const int cbase = w * SLICE;
  const size_t bq = (size_t)b * NL + q0;
  const size_t mrow0 = bq * NL;
  const size_t lrow = mrow0 + (size_t)fr * NL + (size_t)(cbase + 4 * kg);

  // ---- Prefetch: B1's entire ew stream (2 rows x 8 x 16B = 64 VGPRs) ----
  // No dependence on phase A; HBM latency hides under the MFMA/exp work.
  const size_t gbA = (bq + 2 * w) * NL + 4 * lane;
  const size_t gbB = (bq + 2 * w + 1) * NL + 4 * lane;
  f32x4 ewA[8], ewB[8];
#pragma unroll
  for (int s2 = 0; s2 < 8; ++s2)
    ewA[s2] = __builtin_nontemporal_load((const f32x4*)(ew + gbA + 256 * s2));
#pragma unroll
  for (int s2 = 0; s2 < 8; ++s2)
    ewB[s2] = __builtin_nontemporal_load((const f32x4*)(ew + gbB + 256 * s2));

  // Q fragments (temperature folded in)
  bf16x8 a0, a1;
  if constexpr (WS) {
    const u16* qp = qs + (bq + fr) * ND + kg * 8;
    a0 = *(const bf16x8*)qp;
    a1 = *(const bf16x8*)(qp + 32);
  } else {
    const float* qp = q + (bq + fr) * ND + kg * 8;
#pragma unroll
    for (int i = 0; i < 8; ++i) {
      a0[i] = (short)f2bf(qp[i] * 0.125f);
      a1[i] = (short)f2bf(qp[i + 32] * 0.125f);
    }
  }

  // mask bit-words for this lane's (row fr, 256-col slice)
  uint32_t mw[8];
  if constexpr (WS) {
    const uint32_t* mbr = mb + (bq + fr) * (NL / 32) + (cbase >> 5);
#pragma unroll
    for (int u = 0; u < 8; ++u) mw[u] = mbr[u];
  }

  // ---- Phase A: S^T = mfma(K,Q); e = exp(masked S) -> swizzled LDS tile ----
  float rs = 0.f;
#pragma unroll
  for (int ti = 0; ti < NT; ++ti) {
    const int c0 = cbase + ti * 16;
    bf16x8 b0, b1;
    loadKfrag<WS>(k, kb, b, c0 + fr, kg, b0, b1);
    f32x4 s = {0.f, 0.f, 0.f, 0.f};
    s = MFMA(b0, a0, s, 0, 0, 0);   // lane holds S[q=fr][k=c0+4kg+j]
    s = MFMA(b1, a1, s, 0, 0, 0);
    uint32_t nib;
    if constexpr (WS) nib = (mw[ti >> 1] >> (16 * (ti & 1) + 4 * kg)) & 0xFu;
    else              nib = mnib<MMODE>(mask, lrow + (size_t)(ti * 16));
    const float e0 = (nib & 1u) ? 0.f : __expf(s[0]);
    const float e1 = (nib & 2u) ? 0.f : __expf(s[1]);
    const float e2 = (nib & 4u) ? 0.f : __expf(s[2]);
    const float e3 = (nib & 8u) ? 0.f : __expf(s[3]);
    rs += (e0 + e1) + (e2 + e3);
    u32x2 ep;
    ep[0] = (uint32_t)f2bf(e0) | ((uint32_t)f2bf(e1) << 16);
    ep[1] = (uint32_t)f2bf(e2) | ((uint32_t)f2bf(e3) << 16);
    *(u32x2*)(els + fr * ROWU + (swzb((c0 + 4 * kg) * 2) >> 2)) = ep;
  }
  rs += __shfl_xor(rs, 16, 64);
  rs += __shfl_xor(rs, 32, 64);
  if (lane < 16) rsums[w * QT + fr] = rs;
  __syncthreads();

  // ---- Phase B1: row-contiguous streaming; ew already in registers ----
  auto b1row = [&](int rr, const f32x4* w4) {
    float inv = 0.f;
#pragma unroll
    for (int ww = 0; ww < NW; ++ww) inv += rsums[ww * QT + rr];
    inv = 1.0f / inv;
    float* atp = attn + (bq + rr) * NL + 4 * lane;
    uint32_t* lrp = els + rr * ROWU;
    u32x2 el8[8];
#pragma unroll
    for (int s2 = 0; s2 < 8; ++s2)
      el8[s2] = *(const u32x2*)(lrp + (swzb(512 * s2 + 8 * lane) >> 2));
#pragma unroll
    for (int s2 = 0; s2 < 8; ++s2) {
      f32x4 p;
      p[0] = bflo2f(el8[s2][0]) * inv * w4[s2][0];
      p[1] = bfhi2f(el8[s2][0]) * inv * w4[s2][1];
      p[2] = bflo2f(el8[s2][1]) * inv * w4[s2][2];
      p[3] = bfhi2f(el8[s2][1]) * inv * w4[s2][3];
      __builtin_nontemporal_store(p, (f32x4*)(atp + 256 * s2));
      u32x2 pp;
      pp[0] = (uint32_t)f2bf(p[0]) | ((uint32_t)f2bf(p[1]) << 16);
      pp[1] = (uint32_t)f2bf(p[2]) | ((uint32_t)f2bf(p[3]) << 16);
      *(u32x2*)(lrp + (swzb(512 * s2 + 8 * lane) >> 2)) = pp;
    }
  };
  b1row(2 * w, ewA);
  b1row(2 * w + 1, ewB);
  __syncthreads();

  // ---- Phase B2: PV MFMA, P A-fragments straight from LDS ----
  f32x4 oA[4] = {{0.f,0.f,0.f,0.f},{0.f,0.f,0.f,0.f},{0.f,0.f,0.f,0.f},{0.f,0.f,0.f,0.f}};
#pragma unroll
  for (int gi = 0; gi < NT / 2; ++gi) {
    union { u32x4 u; bf16x8 v8; } pu;
    pu.u = *(const u32x4*)(els + fr * ROWU + (swzb((cbase + 32 * gi + 8 * kg) * 2) >> 2));
    const bf16x8 pa = pu.v8;
    const int kk = cbase + gi * 32 + kg * 8;
    if constexpr (WS) {
      const u16* vp = vt + ((size_t)(b * ND + fr)) * NL + kk;   // VT[d][k]
      oA[0] = MFMA(pa, *(const bf16x8*)(vp),           oA[0], 0, 0, 0);
      oA[1] = MFMA(pa, *(const bf16x8*)(vp + 16 * NL), oA[1], 0, 0, 0);
      oA[2] = MFMA(pa, *(const bf16x8*)(vp + 32 * NL), oA[2], 0, 0, 0);
      oA[3] = MFMA(pa, *(const bf16x8*)(vp + 48 * NL), oA[3], 0, 0, 0);
    } else {
#pragma unroll
      for (int dt = 0; dt < 4; ++dt) {
        bf16x8 vf;
#pragma unroll
        for (int i = 0; i < 8; ++i)
          vf[i] = (short)f2bf(v[((size_t)(b * NL + kk + i)) * ND + dt * 16 + fr]);
        oA[dt] = MFMA(pa, vf, oA[dt], 0, 0, 0);
      }
    }
  }
  __syncthreads();   // els reads done; safe to reuse as out-staging

  // ---- 4-round staged cross-wave out reduction (osta aliases els) ----
  float* osta = (float*)els;
  f32x4 acc = {0.f, 0.f, 0.f, 0.f};
  const int rrr = tid >> 4;
  const int d4 = (tid & 15) * 4;
#pragma unroll
  for (int round = 0; round < NW / 2; ++round) {
    if ((w >> 1) == round) {
      float* od = osta + (w & 1) * (QT * ND);
#pragma unroll
      for (int dt = 0; dt < 4; ++dt)
#pragma unroll
        for (int j = 0; j < 4; ++j)
          od[(4 * kg + j) * ND + dt * 16 + fr] = oA[dt][j];
    }
    __syncthreads();
    if (tid < QT * ND / 4) {
      acc += *(const f32x4*)(osta + rrr * ND + d4) +
             *(const f32x4*)(osta + QT * ND + rrr * ND + d4);
    }
    __syncthreads();
  }
  if (tid < QT * ND / 4)
    *(f32x4*)(out + (bq + rrr) * ND + d4) = acc;
}

__global__ void __launch_bounds__(NTHREADS, 4)
attn_ws(const float* __restrict__ q, const float* __restrict__ k,
        const float* __restrict__ v, const float* __restrict__ ew,
        const u16* __restrict__ qs, const u16* __restrict__ kb,
        const u16* __restrict__ vt, const uint32_t* __restrict__ mb,
        float* __restrict__ out, float* __restrict__ attn) {
  extern __shared__ uint32_t els[];
  __shared__ float rsums[NW * QT];
  attn_core<0, true>(q, k, v, ew, nullptr, qs, kb, vt, mb, out, attn, els, rsums);
}

__global__ void __launch_bounds__(NTHREADS, 4)
attn_fb(const float* __restrict__ q, const float* __restrict__ k,
        const float* __restrict__ v, const float* __restrict__ ew,
        const void* __restrict__ mask,
        float* __restrict__ out, float* __restrict__ attn) {
  extern __shared__ uint32_t els[];
  __shared__ float rsums[NW * QT];
  __shared__ int s_mode;
  if (threadIdx.x < 64) {
    const uint32_t x = ((const uint32_t*)mask)[threadIdx.x];
    const int all01 = __all(x <= 1u);
    const int allf  = __all(x == 0u || x == 0x3F800000u);
    const int oddz  = __all(((threadIdx.x & 1) == 0) || (x == 0u));
    if (threadIdx.x == 0) s_mode = all01 ? (oddz ? 3 : 0) : (allf ? 2 : 1);
  }
  __syncthreads();
  switch (s_mode) {
    case 0:  attn_core<0, false>(q, k, v, ew, mask, nullptr, nullptr, nullptr, nullptr, out, attn, els, rsums); break;
    case 1:  attn_core<1, false>(q, k, v, ew, mask, nullptr, nullptr, nullptr, nullptr, out, attn, els, rsums); break;
    case 2:  attn_core<2, false>(q, k, v, ew, mask, nullptr, nullptr, nullptr, nullptr, out, attn, els, rsums); break;
    default: attn_core<3, false>(q, k, v, ew, mask, nullptr, nullptr, nullptr, nullptr, out, attn, els, rsums); break;
  }
}

// prep: q*0.125 -> bf16 qs ; k -> bf16 kb
__global__ void __launch_bounds__(256)
prep_qk(const float* __restrict__ q, const float* __restrict__ k,
        u16* __restrict__ qs, u16* __restrict__ kb) {
  const size_t NQ4 = (size_t)NB * NL * ND / 4;
  const size_t i = (size_t)blockIdx.x * 256 + threadIdx.x;
  f32x4 val;
  u16* dst;
  if (i < NQ4) {
    val = ((const f32x4*)q)[i];
    val *= 0.125f;
    dst = qs + i * 4;
  } else {
    val = ((const f32x4*)k)[i - NQ4];
    dst = kb + (i - NQ4) * 4;
  }
  u16x4 o;
#pragma unroll
  for (int j = 0; j < 4; ++j) o[j] = f2bf(val[j]);
  *(u16x4*)dst = o;
}

// prep: v -> bf16 V^T (per-batch 64x2048)
__global__ void __launch_bounds__(256)
prep_vt(const float* __restrict__ v, u16* __restrict__ vt) {
  __shared__ float t[64 * 68];
  const int b = blockIdx.y;
  const int k0 = blockIdx.x * 64;
  const int tid = threadIdx.x;
  const int rr = tid >> 4;
  const int c4 = (tid & 15) * 4;
#pragma unroll
  for (int i = 0; i < 4; ++i) {
    const int r = rr + 16 * i;
    const f32x4 val = *(const f32x4*)(v + ((size_t)(b * NL + k0 + r)) * ND + c4);
    *(f32x4*)(t + r * 68 + c4) = val;
  }
  __syncthreads();
#pragma unroll
  for (int i = 0; i < 4; ++i) {
    const int d = rr + 16 * i;
    u16x4 o;
#pragma unroll
    for (int j = 0; j < 4; ++j) o[j] = f2bf(t[(c4 + j) * 68 + d]);
    *(u16x4*)(vt + ((size_t)(b * ND + d)) * NL + k0 + c4) = o;
  }
}

// prep: pack mask -> 1 bit/element (u32 covers 32 consecutive k of one row)
__global__ void __launch_bounds__(256)
prep_mask(const void* __restrict__ mask, uint32_t* __restrict__ mb) {
  __shared__ int pm;
  if (threadIdx.x < 64) {
    const uint32_t x = ((const uint32_t*)mask)[threadIdx.x];
    const int all01 = __all(x <= 1u);
    const int allf  = __all(x == 0u || x == 0x3F800000u);
    const int oddz  = __all(((threadIdx.x & 1) == 0) || (x == 0u));
    if (threadIdx.x == 0) pm = all01 ? (oddz ? 3 : 0) : (allf ? 2 : 1);
  }
  __syncthreads();
  const int mode = pm;
  const size_t t = (size_t)blockIdx.x * 256 + threadIdx.x;
  uint32_t bits = 0;
  if (mode == 1) {
    const u32x4 x0 = *(((const u32x4*)mask) + t * 2);
    const u32x4 x1 = *(((const u32x4*)mask) + t * 2 + 1);
#pragma unroll
    for (int i = 0; i < 4; ++i)
#pragma unroll
      for (int by = 0; by < 4; ++by) {
        bits |= (((x0[i] >> (8 * by)) & 0xFFu) ? 1u : 0u) << (i * 4 + by);
        bits |= (((x1[i] >> (8 * by)) & 0xFFu) ? 1u : 0u) << (16 + i * 4 + by);
      }
  } else if (mode == 0 || mode == 2) {
#pragma unroll
    for (int c = 0; c < 8; ++c) {
      const u32x4 x = *(((const u32x4*)mask) + t * 8 + c);
#pragma unroll
      for (int i = 0; i < 4; ++i) bits |= (x[i] ? 1u : 0u) << (c * 4 + i);
    }
  } else {
    const uint32_t* p = (const uint32_t*)mask;
#pragma unroll
    for (int i = 0; i < 32; ++i) bits |= (p[2 * (t * 32 + i)] ? 1u : 0u) << i;
  }
  mb[t] = bits;
}

extern "C" void kernel_launch(void* const* d_in, const int* in_sizes, int n_in,
                              void* d_out, int out_size, void* d_ws, size_t ws_size,
                              hipStream_t stream) {
  const float* q    = (const float*)d_in[0];
  const float* k    = (const float*)d_in[1];
  const float* v    = (const float*)d_in[2];
  const float* ew   = (const float*)d_in[3];
  const void*  mask = d_in[4];
  float* out  = (float*)d_out;
  float* attn = out + (size_t)NB * NL * ND;

  const size_t QE = (size_t)NB * NL * ND;           // 2M elems per matrix
  const size_t MBW = (size_t)NB * NL * (NL / 32);   // 2M mask words
  u16* qs = (u16*)d_ws;
  u16* kb = qs + QE;
  u16* vt = kb + QE;
  uint32_t* mb = (uint32_t*)(vt + QE);

  (void)hipFuncSetAttribute(reinterpret_cast<const void*>(attn_ws),
                            hipFuncAttributeMaxDynamicSharedMemorySize, LDSB);
  (void)hipFuncSetAttribute(reinterpret_cast<const void*>(attn_fb),
                            hipFuncAttributeMaxDynamicSharedMemorySize, LDSB);

  dim3 grid(NB * (NL / QT));   // 2048, 1-D for XCD swizzle
  if (ws_size >= 3 * QE * sizeof(u16) + MBW * sizeof(uint32_t)) {
    prep_qk<<<dim3((unsigned)(2 * QE / 4 / 256)), 256, 0, stream>>>(q, k, qs, kb);
    prep_vt<<<dim3(NL / 64, NB), 256, 0, stream>>>(v, vt);
    prep_mask<<<dim3((unsigned)(MBW / 256)), 256, 0, stream>>>(mask, mb);
    attn_ws<<<grid, NTHREADS, LDSB, stream>>>(q, k, v, ew, qs, kb, vt, mb, out, attn);
  } else {
    attn_fb<<<grid, NTHREADS, LDSB, stream>>>(q, k, v, ew, mask, out, attn);
  }
}